// Round 7
// baseline (415.268 us; speedup 1.0000x reference)
//
#include <hip/hip_runtime.h>
#include <cstdint>
#include <cstddef>

#define LSEQ 1024
#define NH   16
#define NX   8

// Moments layout in sums[] (verified round-4/5/6 algebra):
//   sums[0..35]           G upper-tri (Gram of x)
//   sums[36 + ch*16 + e]  C[ch][e] = sum_l x[l,ch]*P[l,e]   (ch 0..7, e 0..15)
//   sums[163 + m]         S_m = sum_l sin(m*pi*pos), m=1..16
//   sums[179 + m]         C_m = sum_l cos(m*pi*pos), m=1..16
//
// Wave split of the 196 accumulators (A[64] per lane, all STATIC indices):
//   w0: G(36) + S_m(16);  w1: C_m(16) + C ch0,1;  w2: C ch2,3,4;  w3: C ch5,6,7
//
// CRITICAL codegen constraints learned rounds 3-6:
//  * __launch_bounds__ min-waves must stay 1 (asking 4 capped VGPR at 64 -> spill).
//  * NO runtime-indexed access to A[] anywhere: a single non-unrollable A[j]
//    demotes the whole array to scratch (rounds 4-6: ~1 GB scratch traffic,
//    VGPR 64-76, 4x slowdown). The butterfly below is macro-instantiated with
//    LITERAL step bounds so every index is compile-time.
__global__ __launch_bounds__(256, 1)
void attn_moments4(const float* __restrict__ x, const float* __restrict__ pos,
                   const float* __restrict__ Wq, const float* __restrict__ Wk,
                   const float* __restrict__ Wv, const float* __restrict__ Wo,
                   float* __restrict__ out) {
    __shared__ float sums[256];
    __shared__ float U_s[128];
    __shared__ float score_s[256];
    __shared__ float attn_s[256];
    __shared__ float M_s[256];
    __shared__ float weff_s[128];

    const int tid  = threadIdx.x;
    const int w    = tid >> 6;
    const int lane = tid & 63;
    const int b    = blockIdx.x;
    const float* xb = x   + (size_t)b * LSEQ * NX;
    const float* pb = pos + (size_t)b * LSEQ;

    float A[64];
    #pragma unroll
    for (int i = 0; i < 64; ++i) A[i] = 0.f;

    // ---------------- main loop: each wave sweeps all rows, own subset ------
    for (int i = 0; i < 16; ++i) {
        const int l = i * 64 + lane;
        const float4 a = *(const float4*)(xb + (size_t)l * 8);
        const float4 c = *(const float4*)(xb + (size_t)l * 8 + 4);
        const float pv = pb[l];
        const float px[8] = {a.x, a.y, a.z, a.w, c.x, c.y, c.z, c.w};
        const float s1 = sinpif(pv), c1 = cospif(pv);
        const float c2x = 2.f * c1;

        if (w == 0) {
            int idx = 0;
            #pragma unroll
            for (int p = 0; p < 8; ++p)
                #pragma unroll
                for (int q = p; q < 8; ++q) { A[idx] += px[p] * px[q]; ++idx; }
            float s = s1, cc = c1, sp = 0.f, cp = 1.f;
            #pragma unroll
            for (int m = 1; m <= 16; ++m) {
                if (m > 1) { const float sn = c2x*s - sp, cn = c2x*cc - cp;
                             sp = s; cp = cc; s = sn; cc = cn; }
                A[35 + m] += s;                       // S_m
            }
        } else if (w == 1) {
            float s = s1, cc = c1, sp = 0.f, cp = 1.f;
            #pragma unroll
            for (int m = 1; m <= 16; ++m) {
                if (m > 1) { const float sn = c2x*s - sp, cn = c2x*cc - cp;
                             sp = s; cp = cc; s = sn; cc = cn; }
                A[m - 1] += cc;                       // C_m
                if (m <= 8) {
                    A[16 + 2*(m-1)] += px[0] * s;  A[16 + 2*m - 1] += px[0] * cc;
                    A[32 + 2*(m-1)] += px[1] * s;  A[32 + 2*m - 1] += px[1] * cc;
                }
            }
        } else if (w == 2) {
            float s = s1, cc = c1, sp = 0.f, cp = 1.f;
            #pragma unroll
            for (int m = 1; m <= 8; ++m) {
                if (m > 1) { const float sn = c2x*s - sp, cn = c2x*cc - cp;
                             sp = s; cp = cc; s = sn; cc = cn; }
                A[ 0 + 2*(m-1)] += px[2] * s;  A[ 0 + 2*m - 1] += px[2] * cc;
                A[16 + 2*(m-1)] += px[3] * s;  A[16 + 2*m - 1] += px[3] * cc;
                A[32 + 2*(m-1)] += px[4] * s;  A[32 + 2*m - 1] += px[4] * cc;
            }
        } else {
            float s = s1, cc = c1, sp = 0.f, cp = 1.f;
            #pragma unroll
            for (int m = 1; m <= 8; ++m) {
                if (m > 1) { const float sn = c2x*s - sp, cn = c2x*cc - cp;
                             sp = s; cp = cc; s = sn; cc = cn; }
                A[ 0 + 2*(m-1)] += px[5] * s;  A[ 0 + 2*m - 1] += px[5] * cc;
                A[16 + 2*(m-1)] += px[6] * s;  A[16 + 2*m - 1] += px[6] * cc;
                A[32 + 2*(m-1)] += px[7] * s;  A[32 + 2*m - 1] += px[7] * cc;
            }
        }
    }

    // ------- value-halving butterfly, LITERAL stage bounds (keeps A in VGPRs):
    // after all stages, lane g holds total-over-lanes of original A[g] in A[0].
#define BFLY_STAGE(STEP)                                                     \
    {                                                                        \
        const bool hi = (lane & STEP) != 0;                                  \
        _Pragma("unroll")                                                    \
        for (int j = 0; j < STEP; ++j) {                                     \
            const float send = hi ? A[j] : A[j + STEP];                      \
            const float recv = __shfl_xor(send, STEP);                       \
            A[j] = (hi ? A[j + STEP] : A[j]) + recv;                         \
        }                                                                    \
    }
    BFLY_STAGE(32)
    BFLY_STAGE(16)
    BFLY_STAGE(8)
    BFLY_STAGE(4)
    BFLY_STAGE(2)
    BFLY_STAGE(1)
#undef BFLY_STAGE

    {
        int dst = -1;
        if      (w == 0) { if (lane < 36) dst = lane;
                           else if (lane < 52) dst = 164 + (lane - 36); }
        else if (w == 1) { if (lane < 16) dst = 180 + lane;
                           else if (lane < 48) dst = 36 + (lane - 16); }
        else if (w == 2) { if (lane < 48) dst = 68 + lane; }
        else             { if (lane < 48) dst = 116 + lane; }
        if (dst >= 0) sums[dst] = A[0];
    }
    __syncthreads();

    // ---------------- score assembly (verified algebra) ----------------------
    if (tid < 128) {                        // U[d][y] = sum_x Wq[d,x]*G[x,y]
        const int d = tid >> 3, y = tid & 7;
        float acc = 0.f;
        #pragma unroll
        for (int xx = 0; xx < 8; ++xx) {
            const int p = xx < y ? xx : y;
            const int q = xx < y ? y : xx;
            acc += Wq[d * 8 + xx] * sums[8 * p - (p * (p - 1)) / 2 + (q - p)];
        }
        U_s[tid] = acc;
    }
    __syncthreads();
    {
        const int d = tid >> 4, e = tid & 15;
        float a1 = 0.f, a2 = 0.f, a3 = 0.f;
        #pragma unroll
        for (int y = 0; y < 8; ++y) a1 += U_s[d * 8 + y] * Wk[e * 8 + y];
        #pragma unroll
        for (int xx = 0; xx < 8; ++xx) {
            a2 += Wq[d * 8 + xx] * sums[36 + xx * 16 + e];
            a3 += Wk[e * 8 + xx] * sums[36 + xx * 16 + d];
        }
        const int fi = (d >> 1) + 1, fj = (e >> 1) + 1;
        const int spd = fi + fj;
        const int smd = fi > fj ? fi - fj : fj - fi;
        const float Smp = sums[163 + spd];
        const float Cmp = sums[179 + spd];
        const float Sms = (smd == 0) ? 0.f : sums[163 + smd];
        const float Cms = (smd == 0) ? (float)LSEQ : sums[179 + smd];
        const bool de = !(d & 1), ee = !(e & 1);
        float Dv;
        if (de && ee)       Dv = 0.5f * (Cms - Cmp);
        else if (de && !ee) Dv = 0.5f * (Smp + (fi >= fj ? 1.f : -1.f) * Sms);
        else if (!de && ee) Dv = 0.5f * (Smp + (fj >= fi ? 1.f : -1.f) * Sms);
        else                Dv = 0.5f * (Cms + Cmp);
        score_s[tid] = (a1 + a2 + a3 + Dv) * 0.03125f;   // 1/sqrt(1024)
    }
    __syncthreads();

    if (tid < 16) {                         // softmax row per thread
        float mx = -1e30f;
        #pragma unroll
        for (int e = 0; e < 16; ++e) mx = fmaxf(mx, score_s[tid * 16 + e]);
        float ex[16], sum = 0.f;
        #pragma unroll
        for (int e = 0; e < 16; ++e) { ex[e] = __expf(score_s[tid * 16 + e] - mx); sum += ex[e]; }
        const float inv = 1.f / sum;
        #pragma unroll
        for (int e = 0; e < 16; ++e) attn_s[tid * 16 + e] = ex[e] * inv;
    }
    __syncthreads();
    {
        const int h = tid >> 4, e = tid & 15;
        float acc = 0.f;
        #pragma unroll
        for (int d = 0; d < 16; ++d) acc += Wo[h * 16 + d] * attn_s[d * 16 + e];
        M_s[tid] = acc;
    }
    __syncthreads();
    if (tid < 128) {
        const int h = tid >> 3, xx = tid & 7;
        float acc = 0.f;
        #pragma unroll
        for (int e = 0; e < 16; ++e) acc += M_s[h * 16 + e] * Wv[e * 8 + xx];
        weff_s[tid] = acc;
    }
    __syncthreads();

    // ---------------- epilogue: out = x * W_eff^T, 2 rows x 2 passes --------
    #pragma unroll
    for (int pass = 0; pass < 2; ++pass) {
        float xr[2][8];
        #pragma unroll
        for (int r = 0; r < 2; ++r) {
            const int l = pass * 512 + r * 256 + tid;
            const float4 a = *(const float4*)(xb + (size_t)l * 8);
            const float4 c = *(const float4*)(xb + (size_t)l * 8 + 4);
            xr[r][0]=a.x; xr[r][1]=a.y; xr[r][2]=a.z; xr[r][3]=a.w;
            xr[r][4]=c.x; xr[r][5]=c.y; xr[r][6]=c.z; xr[r][7]=c.w;
        }
        float o[2][16];
        #pragma unroll
        for (int h = 0; h < 16; ++h) {
            const float4 wA = *(const float4*)(weff_s + h * 8);
            const float4 wB = *(const float4*)(weff_s + h * 8 + 4);
            #pragma unroll
            for (int r = 0; r < 2; ++r) {
                o[r][h] = xr[r][0]*wA.x + xr[r][1]*wA.y + xr[r][2]*wA.z + xr[r][3]*wA.w
                        + xr[r][4]*wB.x + xr[r][5]*wB.y + xr[r][6]*wB.z + xr[r][7]*wB.w;
            }
        }
        #pragma unroll
        for (int r = 0; r < 2; ++r) {
            const int l = pass * 512 + r * 256 + tid;
            const size_t base = ((size_t)b * LSEQ + l) * NH;
            #pragma unroll
            for (int g = 0; g < 4; ++g)
                *(float4*)(out + base + g * 4) =
                    make_float4(o[r][g*4+0], o[r][g*4+1], o[r][g*4+2], o[r][g*4+3]);
        }
    }
}

extern "C" void kernel_launch(void* const* d_in, const int* in_sizes, int n_in,
                              void* d_out, int out_size, void* d_ws, size_t ws_size,
                              hipStream_t stream) {
    const float* x   = (const float*)d_in[0];
    const float* pos = (const float*)d_in[1];
    const float* Wq  = (const float*)d_in[2];
    const float* Wk  = (const float*)d_in[3];
    const float* Wv  = (const float*)d_in[4];
    const float* Wo  = (const float*)d_in[5];
    float* out = (float*)d_out;
    const int B = in_sizes[1] / LSEQ;   // pos has B*L elements
    attn_moments4<<<B, 256, 0, stream>>>(x, pos, Wq, Wk, Wv, Wo, out);
}

// Round 8
// 101.526 us; speedup vs baseline: 4.0903x; 4.0903x over previous
//
#include <hip/hip_runtime.h>
#include <cstdint>
#include <cstddef>

#define LSEQ 1024
#define NH   16
#define NX   8

// Moments layout in sums[] (algebra verified rounds 4-7, absmax 0.00195):
//   sums[0..35]           G upper-tri (Gram of x): G[p][q] at 8p - p(p-1)/2 + (q-p)
//   sums[36 + ch*16 + e]  C[ch][e] = sum_l x[l,ch]*P[l,e]   (ch 0..7, e 0..15)
//   sums[163 + m]         S_m = sum_l sin(m*pi*pos), m=1..16
//   sums[179 + m]         C_m = sum_l cos(m*pi*pos), m=1..16
//
// Wave split of the 196 accumulators (<=52 per lane):
//   w0: G(36)+S_m(16); w1: C_m(16)+C ch0,1(32); w2: C ch2,3,4(48); w3: C ch5,6,7(48)
//
// Codegen rules learned rounds 3-7 on this compiler:
//  * __launch_bounds__ min-waves stays 1 (min-waves 4 capped VGPR at 64 -> spill).
//  * Local arrays stay in VGPRs ONLY with round-1-style usage: static indices
//    AND plain scalar dataflow. The value-halving shuffle butterfly (rounds
//    5-7) demoted A[] to scratch (~1 GB scratch traffic, VALUBusy 7%).
//    Reduction below is per-element: 6 shfl_xor per A[j], static j. ~300
//    extra shfls per block, once - negligible.
__global__ __launch_bounds__(256, 1)
void attn_moments4(const float* __restrict__ x, const float* __restrict__ pos,
                   const float* __restrict__ Wq, const float* __restrict__ Wk,
                   const float* __restrict__ Wv, const float* __restrict__ Wo,
                   float* __restrict__ out) {
    __shared__ float sums[256];
    __shared__ float U_s[128];
    __shared__ float score_s[256];
    __shared__ float attn_s[256];
    __shared__ float M_s[256];
    __shared__ float weff_s[128];

    const int tid  = threadIdx.x;
    const int w    = tid >> 6;
    const int lane = tid & 63;
    const int b    = blockIdx.x;
    const float* xb = x   + (size_t)b * LSEQ * NX;
    const float* pb = pos + (size_t)b * LSEQ;

    float A[52];
    #pragma unroll
    for (int i = 0; i < 52; ++i) A[i] = 0.f;

    // ---------------- main loop: each wave sweeps all rows, own subset ------
    for (int i = 0; i < 16; ++i) {
        const int l = i * 64 + lane;
        const float4 a = *(const float4*)(xb + (size_t)l * 8);
        const float4 c = *(const float4*)(xb + (size_t)l * 8 + 4);
        const float pv = pb[l];
        const float px[8] = {a.x, a.y, a.z, a.w, c.x, c.y, c.z, c.w};
        const float s1 = sinpif(pv), c1 = cospif(pv);
        const float c2x = 2.f * c1;

        if (w == 0) {
            #pragma unroll
            for (int p = 0; p < 8; ++p)
                #pragma unroll
                for (int q = p; q < 8; ++q)
                    A[p * 8 - (p * (p - 1)) / 2 + (q - p)] += px[p] * px[q];
            float s = s1, cc = c1, sp = 0.f, cp = 1.f;
            #pragma unroll
            for (int m = 1; m <= 16; ++m) {
                if (m > 1) { const float sn = c2x*s - sp, cn = c2x*cc - cp;
                             sp = s; cp = cc; s = sn; cc = cn; }
                A[35 + m] += s;                       // S_m -> A[36..51]
            }
        } else if (w == 1) {
            float s = s1, cc = c1, sp = 0.f, cp = 1.f;
            #pragma unroll
            for (int m = 1; m <= 16; ++m) {
                if (m > 1) { const float sn = c2x*s - sp, cn = c2x*cc - cp;
                             sp = s; cp = cc; s = sn; cc = cn; }
                A[m - 1] += cc;                       // C_m -> A[0..15]
                if (m <= 8) {
                    A[16 + 2*(m-1)] += px[0] * s;  A[16 + 2*m - 1] += px[0] * cc;
                    A[32 + 2*(m-1)] += px[1] * s;  A[32 + 2*m - 1] += px[1] * cc;
                }
            }
        } else if (w == 2) {
            float s = s1, cc = c1, sp = 0.f, cp = 1.f;
            #pragma unroll
            for (int m = 1; m <= 8; ++m) {
                if (m > 1) { const float sn = c2x*s - sp, cn = c2x*cc - cp;
                             sp = s; cp = cc; s = sn; cc = cn; }
                A[ 0 + 2*(m-1)] += px[2] * s;  A[ 0 + 2*m - 1] += px[2] * cc;
                A[16 + 2*(m-1)] += px[3] * s;  A[16 + 2*m - 1] += px[3] * cc;
                A[32 + 2*(m-1)] += px[4] * s;  A[32 + 2*m - 1] += px[4] * cc;
            }
        } else {
            float s = s1, cc = c1, sp = 0.f, cp = 1.f;
            #pragma unroll
            for (int m = 1; m <= 8; ++m) {
                if (m > 1) { const float sn = c2x*s - sp, cn = c2x*cc - cp;
                             sp = s; cp = cc; s = sn; cc = cn; }
                A[ 0 + 2*(m-1)] += px[5] * s;  A[ 0 + 2*m - 1] += px[5] * cc;
                A[16 + 2*(m-1)] += px[6] * s;  A[16 + 2*m - 1] += px[6] * cc;
                A[32 + 2*(m-1)] += px[7] * s;  A[32 + 2*m - 1] += px[7] * cc;
            }
        }
    }

    // ------- per-element wave reduction: 6 scalar shfl_xor per moment -------
    // dst(j) folds to a literal per unrolled j; lane 0 stores to LDS.
    if (w == 0) {
        #pragma unroll
        for (int j = 0; j < 52; ++j) {
            float v = A[j];
            v += __shfl_xor(v, 1);  v += __shfl_xor(v, 2);  v += __shfl_xor(v, 4);
            v += __shfl_xor(v, 8);  v += __shfl_xor(v, 16); v += __shfl_xor(v, 32);
            if (lane == 0) sums[j < 36 ? j : 128 + j] = v;   // 36..51 -> 164..179
        }
    } else if (w == 1) {
        #pragma unroll
        for (int j = 0; j < 48; ++j) {
            float v = A[j];
            v += __shfl_xor(v, 1);  v += __shfl_xor(v, 2);  v += __shfl_xor(v, 4);
            v += __shfl_xor(v, 8);  v += __shfl_xor(v, 16); v += __shfl_xor(v, 32);
            if (lane == 0) sums[j < 16 ? 180 + j : 20 + j] = v; // C_m / C ch0,1
        }
    } else if (w == 2) {
        #pragma unroll
        for (int j = 0; j < 48; ++j) {
            float v = A[j];
            v += __shfl_xor(v, 1);  v += __shfl_xor(v, 2);  v += __shfl_xor(v, 4);
            v += __shfl_xor(v, 8);  v += __shfl_xor(v, 16); v += __shfl_xor(v, 32);
            if (lane == 0) sums[68 + j] = v;                  // C ch2,3,4
        }
    } else {
        #pragma unroll
        for (int j = 0; j < 48; ++j) {
            float v = A[j];
            v += __shfl_xor(v, 1);  v += __shfl_xor(v, 2);  v += __shfl_xor(v, 4);
            v += __shfl_xor(v, 8);  v += __shfl_xor(v, 16); v += __shfl_xor(v, 32);
            if (lane == 0) sums[116 + j] = v;                 // C ch5,6,7
        }
    }
    __syncthreads();

    // ---------------- score assembly (verified algebra) ----------------------
    if (tid < 128) {                        // U[d][y] = sum_x Wq[d,x]*G[x,y]
        const int d = tid >> 3, y = tid & 7;
        float acc = 0.f;
        #pragma unroll
        for (int xx = 0; xx < 8; ++xx) {
            const int p = xx < y ? xx : y;
            const int q = xx < y ? y : xx;
            acc += Wq[d * 8 + xx] * sums[8 * p - (p * (p - 1)) / 2 + (q - p)];
        }
        U_s[tid] = acc;
    }
    __syncthreads();
    {
        const int d = tid >> 4, e = tid & 15;
        float a1 = 0.f, a2 = 0.f, a3 = 0.f;
        #pragma unroll
        for (int y = 0; y < 8; ++y) a1 += U_s[d * 8 + y] * Wk[e * 8 + y];
        #pragma unroll
        for (int xx = 0; xx < 8; ++xx) {
            a2 += Wq[d * 8 + xx] * sums[36 + xx * 16 + e];
            a3 += Wk[e * 8 + xx] * sums[36 + xx * 16 + d];
        }
        const int fi = (d >> 1) + 1, fj = (e >> 1) + 1;
        const int spd = fi + fj;
        const int smd = fi > fj ? fi - fj : fj - fi;
        const float Smp = sums[163 + spd];
        const float Cmp = sums[179 + spd];
        const float Sms = (smd == 0) ? 0.f : sums[163 + smd];
        const float Cms = (smd == 0) ? (float)LSEQ : sums[179 + smd];
        const bool de = !(d & 1), ee = !(e & 1);
        float Dv;
        if (de && ee)       Dv = 0.5f * (Cms - Cmp);
        else if (de && !ee) Dv = 0.5f * (Smp + (fi >= fj ? 1.f : -1.f) * Sms);
        else if (!de && ee) Dv = 0.5f * (Smp + (fj >= fi ? 1.f : -1.f) * Sms);
        else                Dv = 0.5f * (Cms + Cmp);
        score_s[tid] = (a1 + a2 + a3 + Dv) * 0.03125f;   // 1/sqrt(1024)
    }
    __syncthreads();

    if (tid < 16) {                         // softmax row per thread
        float mx = -1e30f;
        #pragma unroll
        for (int e = 0; e < 16; ++e) mx = fmaxf(mx, score_s[tid * 16 + e]);
        float ex[16], sum = 0.f;
        #pragma unroll
        for (int e = 0; e < 16; ++e) { ex[e] = __expf(score_s[tid * 16 + e] - mx); sum += ex[e]; }
        const float inv = 1.f / sum;
        #pragma unroll
        for (int e = 0; e < 16; ++e) attn_s[tid * 16 + e] = ex[e] * inv;
    }
    __syncthreads();
    {
        const int h = tid >> 4, e = tid & 15;
        float acc = 0.f;
        #pragma unroll
        for (int d = 0; d < 16; ++d) acc += Wo[h * 16 + d] * attn_s[d * 16 + e];
        M_s[tid] = acc;
    }
    __syncthreads();
    if (tid < 128) {
        const int h = tid >> 3, xx = tid & 7;
        float acc = 0.f;
        #pragma unroll
        for (int e = 0; e < 16; ++e) acc += M_s[h * 16 + e] * Wv[e * 8 + xx];
        weff_s[tid] = acc;
    }
    __syncthreads();

    // ---------------- epilogue: out = x * W_eff^T, 2 rows x 2 passes --------
    #pragma unroll
    for (int pass = 0; pass < 2; ++pass) {
        float xr[2][8];
        #pragma unroll
        for (int r = 0; r < 2; ++r) {
            const int l = pass * 512 + r * 256 + tid;
            const float4 a = *(const float4*)(xb + (size_t)l * 8);
            const float4 c = *(const float4*)(xb + (size_t)l * 8 + 4);
            xr[r][0]=a.x; xr[r][1]=a.y; xr[r][2]=a.z; xr[r][3]=a.w;
            xr[r][4]=c.x; xr[r][5]=c.y; xr[r][6]=c.z; xr[r][7]=c.w;
        }
        float o[2][16];
        #pragma unroll
        for (int h = 0; h < 16; ++h) {
            const float4 wA = *(const float4*)(weff_s + h * 8);
            const float4 wB = *(const float4*)(weff_s + h * 8 + 4);
            #pragma unroll
            for (int r = 0; r < 2; ++r) {
                o[r][h] = xr[r][0]*wA.x + xr[r][1]*wA.y + xr[r][2]*wA.z + xr[r][3]*wA.w
                        + xr[r][4]*wB.x + xr[r][5]*wB.y + xr[r][6]*wB.z + xr[r][7]*wB.w;
            }
        }
        #pragma unroll
        for (int r = 0; r < 2; ++r) {
            const int l = pass * 512 + r * 256 + tid;
            const size_t base = ((size_t)b * LSEQ + l) * NH;
            #pragma unroll
            for (int g = 0; g < 4; ++g)
                *(float4*)(out + base + g * 4) =
                    make_float4(o[r][g*4+0], o[r][g*4+1], o[r][g*4+2], o[r][g*4+3]);
        }
    }
}

extern "C" void kernel_launch(void* const* d_in, const int* in_sizes, int n_in,
                              void* d_out, int out_size, void* d_ws, size_t ws_size,
                              hipStream_t stream) {
    const float* x   = (const float*)d_in[0];
    const float* pos = (const float*)d_in[1];
    const float* Wq  = (const float*)d_in[2];
    const float* Wk  = (const float*)d_in[3];
    const float* Wv  = (const float*)d_in[4];
    const float* Wo  = (const float*)d_in[5];
    float* out = (float*)d_out;
    const int B = in_sizes[1] / LSEQ;   // pos has B*L elements
    attn_moments4<<<B, 256, 0, stream>>>(x, pos, Wq, Wk, Wv, Wo, out);
}